// Round 2
// baseline (840.097 us; speedup 1.0000x reference)
//
#include <hip/hip_runtime.h>
#include <hip/hip_bf16.h>
#include <cstdint>

typedef __bf16 bf16_t;
typedef __bf16 bf16x4 __attribute__((ext_vector_type(4)));
typedef __bf16 bf16x8 __attribute__((ext_vector_type(8)));
typedef float floatx4 __attribute__((ext_vector_type(4)));

#define LNEPS 1e-5f

__device__ inline void async_copy16(const bf16_t* g, bf16_t* l) {
    __builtin_amdgcn_global_load_lds((const __attribute__((address_space(1))) void*)g,
                                     (__attribute__((address_space(3))) void*)l,
                                     16, 0, 0);
}

// ---------------------------------------------------------------------------
// K-1: convert x[:,1:,:] fp32 -> bf16, contiguous [gr=b*196+l][768]
// ---------------------------------------------------------------------------
__global__ __launch_bounds__(256)
void k_cvt_x(const float* __restrict__ x, bf16_t* __restrict__ xbf) {
    const int vid = blockIdx.x * 256 + threadIdx.x;   // float4 id, 9,633,792 total
    const int row = vid / 192;                        // 0..50175
    const int kv  = vid - row * 192;
    const int b = row / 196, l = row - b * 196;
    const floatx4 f = *(const floatx4*)(x + ((b * 197 + l + 1) * 192 + kv) * 4);
    bf16x4 o;
#pragma unroll
    for (int e = 0; e < 4; e++) o[e] = (bf16_t)f[e];
    *(bf16x4*)(xbf + vid * 4) = o;
}

// ---------------------------------------------------------------------------
// K0: transpose proj_w (768x512 fp32) -> Wt (512x768 bf16), K-contig B operand
// ---------------------------------------------------------------------------
__global__ __launch_bounds__(256)
void k_transpose_w(const float* __restrict__ w, bf16_t* __restrict__ wt) {
    __shared__ bf16_t tile[32][33];
    const int bx = blockIdx.x;            // n-tile (16)
    const int by = blockIdx.y;            // k-tile (24)
    const int tx = threadIdx.x & 31, ty = threadIdx.x >> 5;  // 32x8
    for (int i = ty; i < 32; i += 8)
        tile[i][tx] = (bf16_t)w[(by*32 + i)*512 + bx*32 + tx];
    __syncthreads();
    for (int i = ty; i < 32; i += 8)
        wt[(bx*32 + i)*768 + by*32 + tx] = tile[tx][i];
}

// ---------------------------------------------------------------------------
// K1: xp = xbf @ Wt^T + b, fused per-head LayerNorm; write hn[h][b][n][d] bf16
//     (uncentered; global centering folded into cov stage)
// M = 50176, N-tile = one head (128 cols), K = 768  — m97 structure
// ---------------------------------------------------------------------------
__global__ __launch_bounds__(256, 2)
void k_proj_ln(const bf16_t* __restrict__ xbf, const bf16_t* __restrict__ wt,
               const float* __restrict__ pb, const float* __restrict__ lng,
               const float* __restrict__ lnb, bf16_t* __restrict__ hn)
{
    __shared__ bf16_t As[128*32];
    __shared__ bf16_t Bs[128*32];
    __shared__ float rs_sum[2][128];
    __shared__ float rs_sq[2][128];

    const int t = threadIdx.x;
    const int lane = t & 63;
    const int wv = t >> 6;
    const int wr = wv >> 1, wc = wv & 1;
    const int q = lane >> 4;
    const int c = lane & 15;
    const int h = blockIdx.y;
    const int mt = blockIdx.x;

    const int srow  = t >> 2;
    const int skoff = (t & 3) * 8;
    const int m0 = mt * 128;
    const bf16_t* ag0 = xbf + (m0 + srow) * 768 + skoff;
    const bf16_t* ag1 = xbf + (m0 + srow + 64) * 768 + skoff;
    const bf16_t* bg0 = wt + (h*128 + srow)*768 + skoff;
    const bf16_t* bg1 = wt + (h*128 + srow + 64)*768 + skoff;

    floatx4 acc[4][4];
#pragma unroll
    for (int i = 0; i < 4; i++)
#pragma unroll
        for (int j = 0; j < 4; j++)
#pragma unroll
            for (int r = 0; r < 4; r++) acc[i][j][r] = 0.f;

    for (int k0 = 0; k0 < 768; k0 += 32) {
        __syncthreads();
        async_copy16(ag0 + k0, &As[t*8]);
        async_copy16(ag1 + k0, &As[2048 + t*8]);
        async_copy16(bg0 + k0, &Bs[t*8]);
        async_copy16(bg1 + k0, &Bs[2048 + t*8]);
        __syncthreads();
        bf16x8 af[4], bfr[4];
#pragma unroll
        for (int i = 0; i < 4; i++)
            af[i] = *(const bf16x8*)&As[(wr*64 + i*16 + c)*32 + q*8];
#pragma unroll
        for (int j = 0; j < 4; j++)
            bfr[j] = *(const bf16x8*)&Bs[(wc*64 + j*16 + c)*32 + q*8];
#pragma unroll
        for (int i = 0; i < 4; i++)
#pragma unroll
            for (int j = 0; j < 4; j++)
                acc[i][j] = __builtin_amdgcn_mfma_f32_16x16x32_bf16(af[i], bfr[j], acc[i][j], 0, 0, 0);
    }

    // epilogue: +bias, LayerNorm over the 128 cols (= one head) per row
    float bias[4], gg[4], bb[4];
#pragma unroll
    for (int j = 0; j < 4; j++) {
        const int d = wc*64 + j*16 + c;
        bias[j] = pb[h*128 + d];
        gg[j]   = lng[d];
        bb[j]   = lnb[d];
    }
#pragma unroll
    for (int i = 0; i < 4; i++)
#pragma unroll
        for (int j = 0; j < 4; j++)
#pragma unroll
            for (int r = 0; r < 4; r++) acc[i][j][r] += bias[j];

#pragma unroll
    for (int i = 0; i < 4; i++) {
#pragma unroll
        for (int r = 0; r < 4; r++) {
            float s = 0.f, s2 = 0.f;
#pragma unroll
            for (int j = 0; j < 4; j++) { const float v = acc[i][j][r]; s += v; s2 += v*v; }
#pragma unroll
            for (int o = 1; o < 16; o <<= 1) { s += __shfl_xor(s, o); s2 += __shfl_xor(s2, o); }
            if (c == 0) {
                const int row = wr*64 + i*16 + q*4 + r;
                rs_sum[wc][row] = s;
                rs_sq[wc][row]  = s2;
            }
        }
    }
    __syncthreads();
#pragma unroll
    for (int i = 0; i < 4; i++) {
#pragma unroll
        for (int r = 0; r < 4; r++) {
            const int row = wr*64 + i*16 + q*4 + r;
            const float mu = (rs_sum[0][row] + rs_sum[1][row]) * (1.f/128.f);
            const float ms = (rs_sq[0][row]  + rs_sq[1][row])  * (1.f/128.f);
            const float rstd = rsqrtf(ms - mu*mu + LNEPS);
            const int gm = m0 + row;
            const int bI = gm / 196, l = gm - bI*196;
            bf16_t* dst = hn + (((h*256 + bI)*196 + l) << 7);
#pragma unroll
            for (int j = 0; j < 4; j++) {
                const float v = (acc[i][j][r] - mu)*rstd*gg[j] + bb[j];
                dst[wc*64 + j*16 + c] = (bf16_t)v;
            }
        }
    }
}

// ---------------------------------------------------------------------------
// K2: per (p,b): raw = x1^T @ x2 (K=196 padded to 224), centering correction,
//     column L2 normalize over d, write cov[b][p][d][e] fp32
// ---------------------------------------------------------------------------
__global__ __launch_bounds__(256, 2)
void k_cov(const bf16_t* __restrict__ hn, float* __restrict__ cov)
{
    __shared__ bf16_t x1s[128*40];   // [d][n_local], row stride 40 el (80B, 16B aligned)
    __shared__ bf16_t x2s[128*40];
    __shared__ float rs1[128], rs2[128];
    __shared__ float colsq[2][128];
    __shared__ float nrm_inv[128];
    __shared__ float mu_s[2];

    const int t = threadIdx.x;
    const int lane = t & 63;
    const int wv = t >> 6;
    const int wr = wv >> 1, wc = wv & 1;
    const int q = lane >> 4;
    const int c = lane & 15;
    const int b = blockIdx.x;
    const int p = blockIdx.y;

    const bf16_t* X1 = hn + (((p*256 + b)*196) << 7);
    const bf16_t* X2 = hn + ((((p+1)*256 + b)*196) << 7);

    { // column sums (for folded global-centering correction)
        const bf16_t* S = (t < 128) ? X1 : X2;
        const int d = t & 127;
        float s = 0.f;
        for (int n = 0; n < 196; n++) s += (float)S[(n << 7) + d];
        if (t < 128) rs1[d] = s; else rs2[d] = s;
    }
    __syncthreads();
    if (wv == 0) {
        float s = rs1[lane] + rs1[lane + 64];
#pragma unroll
        for (int o = 1; o < 64; o <<= 1) s += __shfl_xor(s, o);
        if (lane == 0) mu_s[0] = s * (1.f/(196.f*128.f));
    } else if (wv == 1) {
        float s = rs2[lane] + rs2[lane + 64];
#pragma unroll
        for (int o = 1; o < 64; o <<= 1) s += __shfl_xor(s, o);
        if (lane == 0) mu_s[1] = s * (1.f/(196.f*128.f));
    }

    floatx4 acc[4][4];
#pragma unroll
    for (int i = 0; i < 4; i++)
#pragma unroll
        for (int j = 0; j < 4; j++)
#pragma unroll
            for (int r = 0; r < 4; r++) acc[i][j][r] = 0.f;

    const int nl = t >> 3;         // 0..31
    const int d0 = (t & 7) * 16;   // 0..112

    for (int n0 = 0; n0 < 224; n0 += 32) {
        __syncthreads();
        const int n = n0 + nl;
        bf16x8 va, vb, wa, wb;
        if (n < 196) {
            const bf16_t* s1 = X1 + (n << 7) + d0;
            const bf16_t* s2 = X2 + (n << 7) + d0;
            va = *(const bf16x8*)s1;
            vb = *(const bf16x8*)(s1 + 8);
            wa = *(const bf16x8*)s2;
            wb = *(const bf16x8*)(s2 + 8);
        } else {
#pragma unroll
            for (int e = 0; e < 8; e++) {
                va[e] = (bf16_t)0.f; vb[e] = (bf16_t)0.f;
                wa[e] = (bf16_t)0.f; wb[e] = (bf16_t)0.f;
            }
        }
#pragma unroll
        for (int e = 0; e < 8; e++) {   // LDS transpose write
            x1s[(d0 + e)*40 + nl]     = va[e];
            x1s[(d0 + 8 + e)*40 + nl] = vb[e];
            x2s[(d0 + e)*40 + nl]     = wa[e];
            x2s[(d0 + 8 + e)*40 + nl] = wb[e];
        }
        __syncthreads();
        bf16x8 af[4], bfr[4];
#pragma unroll
        for (int i = 0; i < 4; i++)
            af[i] = *(const bf16x8*)&x1s[(wr*64 + i*16 + c)*40 + q*8];
#pragma unroll
        for (int j = 0; j < 4; j++)
            bfr[j] = *(const bf16x8*)&x2s[(wc*64 + j*16 + c)*40 + q*8];
#pragma unroll
        for (int i = 0; i < 4; i++)
#pragma unroll
            for (int j = 0; j < 4; j++)
                acc[i][j] = __builtin_amdgcn_mfma_f32_16x16x32_bf16(af[i], bfr[j], acc[i][j], 0, 0, 0);
    }

    const float mu1 = mu_s[0], mu2 = mu_s[1];
    const float invL = 1.f/196.f;
    float csq[4] = {0.f, 0.f, 0.f, 0.f};
#pragma unroll
    for (int i = 0; i < 4; i++)
#pragma unroll
        for (int j = 0; j < 4; j++)
#pragma unroll
            for (int r = 0; r < 4; r++) {
                const int d = wr*64 + i*16 + q*4 + r;
                const int e = wc*64 + j*16 + c;
                const float v = acc[i][j][r]*invL - mu2*rs1[d]*invL - mu1*rs2[e]*invL + mu1*mu2;
                acc[i][j][r] = v;
                csq[j] += v*v;
            }
#pragma unroll
    for (int j = 0; j < 4; j++) {
        float s = csq[j];
        s += __shfl_xor(s, 16);
        s += __shfl_xor(s, 32);
        csq[j] = s;
    }
    if (q == 0) {
#pragma unroll
        for (int j = 0; j < 4; j++) colsq[wr][wc*64 + j*16 + c] = csq[j];
    }
    __syncthreads();
    if (t < 128) {
        const float nr = sqrtf(colsq[0][t] + colsq[1][t]);
        nrm_inv[t] = 1.f / fmaxf(nr, 1e-12f);
    }
    __syncthreads();
    float* dst = cov + ((long)b*3 + p)*16384;
#pragma unroll
    for (int i = 0; i < 4; i++)
#pragma unroll
        for (int j = 0; j < 4; j++) {
            const int e = wc*64 + j*16 + c;
            const float ni = nrm_inv[e];
#pragma unroll
            for (int r = 0; r < 4; r++) {
                const int d = wr*64 + i*16 + q*4 + r;
                dst[(d << 7) + e] = acc[i][j][r] * ni;
            }
        }
}

// ---------------------------------------------------------------------------
// K3a: conv1 (stride2 VALID) + exact GELU -> z1[b][o][63][63] fp32
// ---------------------------------------------------------------------------
__global__ __launch_bounds__(256)
void k_conv1(const float* __restrict__ cov, const float* __restrict__ w1,
             float* __restrict__ z1)
{
    __shared__ float W[27];
    const int t = threadIdx.x;
    const int b = blockIdx.x, o = blockIdx.y;
    if (t < 27) W[t] = w1[o*27 + t];
    __syncthreads();
    const float* C = cov + (long)b*3*16384;
    float* Z = z1 + ((long)b*3 + o)*3969;
    for (int idx = t; idx < 3969; idx += 256) {
        const int y = idx / 63, xx = idx - y*63;
        float a = 0.f;
#pragma unroll
        for (int i = 0; i < 3; i++) {
            const float* Ci = C + i*16384 + (2*y)*128 + 2*xx;
            const float* Wi = &W[i*9];
            a += Ci[0]*Wi[0]   + Ci[1]*Wi[1]   + Ci[2]*Wi[2]
               + Ci[128]*Wi[3] + Ci[129]*Wi[4] + Ci[130]*Wi[5]
               + Ci[256]*Wi[6] + Ci[257]*Wi[7] + Ci[258]*Wi[8];
        }
        Z[idx] = 0.5f*a*(1.0f + erff(a*0.70710678118654752f));
    }
}

// ---------------------------------------------------------------------------
// K3b: conv2 (stride2 VALID) -> flat[b][2883] fp32
// ---------------------------------------------------------------------------
__global__ __launch_bounds__(256)
void k_conv2(const float* __restrict__ z1, const float* __restrict__ w2,
             float* __restrict__ flat)
{
    __shared__ float Z[3*3969];
    __shared__ float W[81];
    const int t = threadIdx.x, b = blockIdx.x;
    if (t < 81) W[t] = w2[t];
    const float* src = z1 + (long)b*3*3969;
    for (int idx = t; idx < 3*3969; idx += 256) Z[idx] = src[idx];
    __syncthreads();
    for (int idx = t; idx < 2883; idx += 256) {
        const int o = idx / 961, rem = idx - o*961;
        const int y = rem / 31, xx = rem - y*31;
        float a = 0.f;
#pragma unroll
        for (int i = 0; i < 3; i++) {
            const float* Zi = Z + i*3969 + (2*y)*63 + 2*xx;
            const float* Wi = &W[(o*3+i)*9];
            a += Zi[0]*Wi[0]   + Zi[1]*Wi[1]   + Zi[2]*Wi[2]
               + Zi[63]*Wi[3]  + Zi[64]*Wi[4]  + Zi[65]*Wi[5]
               + Zi[126]*Wi[6] + Zi[127]*Wi[7] + Zi[128]*Wi[8];
        }
        flat[(long)b*2883 + idx] = a;
    }
}

// ---------------------------------------------------------------------------
// K4: out = 0.5*(cls @ W1 + b1 + flat @ W2 + b2)   (256 x 1000) fp32
// 128 blocks: 32 m-tiles x 8 rows, 4 n-tiles x 256 cols
// ---------------------------------------------------------------------------
__global__ __launch_bounds__(256)
void k_cls(const float* __restrict__ cls, const float* __restrict__ flat,
           const float* __restrict__ W1, const float* __restrict__ b1,
           const float* __restrict__ W2, const float* __restrict__ b2,
           float* __restrict__ out)
{
    __shared__ float fls[8*96];
    const int t = threadIdx.x;
    const int mt = blockIdx.x & 31;
    const int nt = blockIdx.x >> 5;
    const int m0 = mt * 8;
    const int n = nt*256 + t;
    float acc[8] = {0.f,0.f,0.f,0.f,0.f,0.f,0.f,0.f};

    for (int k0 = 0; k0 < 768; k0 += 96) {
        __syncthreads();
        for (int idx = t; idx < 768; idx += 256) {
            const int mm = idx / 96, kk = idx - mm*96;
            fls[idx] = cls[(m0+mm)*768 + k0 + kk];
        }
        __syncthreads();
        if (n < 1000) {
            for (int kk = 0; kk < 96; kk++) {
                const float wvl = W1[(k0+kk)*1000 + n];
#pragma unroll
                for (int mm = 0; mm < 8; mm++) acc[mm] += fls[mm*96+kk]*wvl;
            }
        }
    }
    for (int k0 = 0; k0 < 2883; k0 += 96) {
        int kl = 2883 - k0; if (kl > 96) kl = 96;
        __syncthreads();
        for (int idx = t; idx < 768; idx += 256) {
            const int mm = idx / 96, kk = idx - mm*96;
            if (kk < kl) fls[idx] = flat[(m0+mm)*2883 + k0 + kk];
        }
        __syncthreads();
        if (n < 1000) {
            for (int kk = 0; kk < kl; kk++) {
                const float wvl = W2[(k0+kk)*1000 + n];
#pragma unroll
                for (int mm = 0; mm < 8; mm++) acc[mm] += fls[mm*96+kk]*wvl;
            }
        }
    }
    if (n < 1000) {
        const float bsum = b1[n] + b2[n];
#pragma unroll
        for (int mm = 0; mm < 8; mm++)
            out[(m0+mm)*1000 + n] = 0.5f*(acc[mm] + bsum);
    }
}

// ---------------------------------------------------------------------------
extern "C" void kernel_launch(void* const* d_in, const int* in_sizes, int n_in,
                              void* d_out, int out_size, void* d_ws, size_t ws_size,
                              hipStream_t stream) {
    const float* cls = (const float*)d_in[0];
    const float* x   = (const float*)d_in[1];
    const float* pw  = (const float*)d_in[2];
    const float* pb  = (const float*)d_in[3];
    const float* lng = (const float*)d_in[4];
    const float* lnb = (const float*)d_in[5];
    const float* c1w = (const float*)d_in[6];
    const float* c2w = (const float*)d_in[7];
    const float* w1  = (const float*)d_in[8];
    const float* b1  = (const float*)d_in[9];
    const float* w2  = (const float*)d_in[10];
    const float* b2  = (const float*)d_in[11];

    char* ws = (char*)d_ws;
    // lifetimes: xbf,wt -> k_proj_ln; hn -> k_cov; covb (reuses xbf) -> k_conv1;
    // z1 -> k_conv2; flat -> k_cls
    bf16_t* hn   = (bf16_t*)(ws);                     // [0, 51.4 MB)
    bf16_t* xbf  = (bf16_t*)(ws + 52428800ull);       // [50 MiB, +77.1 MB)
    bf16_t* wt   = (bf16_t*)(ws + 130023424ull);      // [124 MiB, +0.79 MB)
    float*  covb = (float*) (ws + 52428800ull);       // reuse xbf region (dead)
    float*  z1   = (float*) (ws + 104857600ull);      // [100 MiB, +12.2 MB)
    float*  flat = (float*) (ws + 117440512ull);      // [112 MiB, +2.95 MB)
    float*  out  = (float*)d_out;

    k_cvt_x<<<37632, 256, 0, stream>>>(x, xbf);
    k_transpose_w<<<dim3(16, 24), 256, 0, stream>>>(pw, wt);
    k_proj_ln<<<dim3(392, 4), 256, 0, stream>>>(xbf, wt, pb, lng, lnb, hn);
    k_cov<<<dim3(256, 3), 256, 0, stream>>>(hn, covb);
    k_conv1<<<dim3(256, 3), 256, 0, stream>>>(covb, c1w, z1);
    k_conv2<<<dim3(256), 256, 0, stream>>>(z1, c2w, flat);
    k_cls<<<dim3(128), 256, 0, stream>>>(cls, flat, w1, b1, w2, b2, out);
}

// Round 3
// 441.079 us; speedup vs baseline: 1.9046x; 1.9046x over previous
//
#include <hip/hip_runtime.h>
#include <hip/hip_bf16.h>
#include <cstdint>

typedef __bf16 bf16_t;
typedef __bf16 bf16x4 __attribute__((ext_vector_type(4)));
typedef __bf16 bf16x8 __attribute__((ext_vector_type(8)));
typedef float floatx4 __attribute__((ext_vector_type(4)));

#define LNEPS 1e-5f

__device__ inline void async_copy16(const bf16_t* g, bf16_t* l) {
    __builtin_amdgcn_global_load_lds((const __attribute__((address_space(1))) void*)g,
                                     (__attribute__((address_space(3))) void*)l,
                                     16, 0, 0);
}

// ---------------------------------------------------------------------------
// K-1: convert half-batch of x[:,1:,:] fp32 -> bf16 [25088][768]
// ---------------------------------------------------------------------------
__global__ __launch_bounds__(256)
void k_cvt_x(const float* __restrict__ x, bf16_t* __restrict__ xbf, int b0) {
    const int vid = blockIdx.x * 256 + threadIdx.x;   // float4 id, 4,816,896 total
    const int row = vid / 192;                        // 0..25087 (local)
    const int kv  = vid - row * 192;
    const int b = b0 + row / 196, l = row - (row / 196) * 196;
    const floatx4 f = *(const floatx4*)(x + ((b * 197 + l + 1) * 192 + kv) * 4);
    bf16x4 o;
#pragma unroll
    for (int e = 0; e < 4; e++) o[e] = (bf16_t)f[e];
    *(bf16x4*)(xbf + vid * 4) = o;
}

// ---------------------------------------------------------------------------
// K0: transpose proj_w (768x512 fp32) -> Wt (512x768 bf16), K-contig B operand
// ---------------------------------------------------------------------------
__global__ __launch_bounds__(256)
void k_transpose_w(const float* __restrict__ w, bf16_t* __restrict__ wt) {
    __shared__ bf16_t tile[32][33];
    const int bx = blockIdx.x;            // n-tile (16)
    const int by = blockIdx.y;            // k-tile (24)
    const int tx = threadIdx.x & 31, ty = threadIdx.x >> 5;  // 32x8
    for (int i = ty; i < 32; i += 8)
        tile[i][tx] = (bf16_t)w[(by*32 + i)*512 + bx*32 + tx];
    __syncthreads();
    for (int i = ty; i < 32; i += 8)
        wt[(bx*32 + i)*768 + by*32 + tx] = tile[tx][i];
}

// ---------------------------------------------------------------------------
// K1: xp = xbf @ Wt^T + b, fused per-head LayerNorm; write hn[h][b][n][d] bf16
// Half-batch: M = 25088 local rows, m_base = global row offset
// ---------------------------------------------------------------------------
__global__ __launch_bounds__(256, 2)
void k_proj_ln(const bf16_t* __restrict__ xbf, const bf16_t* __restrict__ wt,
               const float* __restrict__ pb, const float* __restrict__ lng,
               const float* __restrict__ lnb, bf16_t* __restrict__ hn, int m_base)
{
    __shared__ bf16_t As[128*32];
    __shared__ bf16_t Bs[128*32];
    __shared__ float rs_sum[2][128];
    __shared__ float rs_sq[2][128];

    const int t = threadIdx.x;
    const int lane = t & 63;
    const int wv = t >> 6;
    const int wr = wv >> 1, wc = wv & 1;
    const int q = lane >> 4;
    const int c = lane & 15;
    const int h = blockIdx.y;
    const int mt = blockIdx.x;

    const int srow  = t >> 2;
    const int skoff = (t & 3) * 8;
    const int m0 = mt * 128;
    const bf16_t* ag0 = xbf + (m0 + srow) * 768 + skoff;
    const bf16_t* ag1 = xbf + (m0 + srow + 64) * 768 + skoff;
    const bf16_t* bg0 = wt + (h*128 + srow)*768 + skoff;
    const bf16_t* bg1 = wt + (h*128 + srow + 64)*768 + skoff;

    floatx4 acc[4][4];
#pragma unroll
    for (int i = 0; i < 4; i++)
#pragma unroll
        for (int j = 0; j < 4; j++)
#pragma unroll
            for (int r = 0; r < 4; r++) acc[i][j][r] = 0.f;

    for (int k0 = 0; k0 < 768; k0 += 32) {
        __syncthreads();
        async_copy16(ag0 + k0, &As[t*8]);
        async_copy16(ag1 + k0, &As[2048 + t*8]);
        async_copy16(bg0 + k0, &Bs[t*8]);
        async_copy16(bg1 + k0, &Bs[2048 + t*8]);
        __syncthreads();
        bf16x8 af[4], bfr[4];
#pragma unroll
        for (int i = 0; i < 4; i++)
            af[i] = *(const bf16x8*)&As[(wr*64 + i*16 + c)*32 + q*8];
#pragma unroll
        for (int j = 0; j < 4; j++)
            bfr[j] = *(const bf16x8*)&Bs[(wc*64 + j*16 + c)*32 + q*8];
#pragma unroll
        for (int i = 0; i < 4; i++)
#pragma unroll
            for (int j = 0; j < 4; j++)
                acc[i][j] = __builtin_amdgcn_mfma_f32_16x16x32_bf16(af[i], bfr[j], acc[i][j], 0, 0, 0);
    }

    float bias[4], gg[4], bb[4];
#pragma unroll
    for (int j = 0; j < 4; j++) {
        const int d = wc*64 + j*16 + c;
        bias[j] = pb[h*128 + d];
        gg[j]   = lng[d];
        bb[j]   = lnb[d];
    }
#pragma unroll
    for (int i = 0; i < 4; i++)
#pragma unroll
        for (int j = 0; j < 4; j++)
#pragma unroll
            for (int r = 0; r < 4; r++) acc[i][j][r] += bias[j];

#pragma unroll
    for (int i = 0; i < 4; i++) {
#pragma unroll
        for (int r = 0; r < 4; r++) {
            float s = 0.f, s2 = 0.f;
#pragma unroll
            for (int j = 0; j < 4; j++) { const float v = acc[i][j][r]; s += v; s2 += v*v; }
#pragma unroll
            for (int o = 1; o < 16; o <<= 1) { s += __shfl_xor(s, o); s2 += __shfl_xor(s2, o); }
            if (c == 0) {
                const int row = wr*64 + i*16 + q*4 + r;
                rs_sum[wc][row] = s;
                rs_sq[wc][row]  = s2;
            }
        }
    }
    __syncthreads();
#pragma unroll
    for (int i = 0; i < 4; i++) {
#pragma unroll
        for (int r = 0; r < 4; r++) {
            const int row = wr*64 + i*16 + q*4 + r;
            const float mu = (rs_sum[0][row] + rs_sum[1][row]) * (1.f/128.f);
            const float ms = (rs_sq[0][row]  + rs_sq[1][row])  * (1.f/128.f);
            const float rstd = rsqrtf(ms - mu*mu + LNEPS);
            const int gm = m_base + m0 + row;
            const int bI = gm / 196, l = gm - bI*196;
            bf16_t* dst = hn + (((h*256 + bI)*196 + l) << 7);
#pragma unroll
            for (int j = 0; j < 4; j++) {
                const float v = (acc[i][j][r] - mu)*rstd*gg[j] + bb[j];
                dst[wc*64 + j*16 + c] = (bf16_t)v;
            }
        }
    }
}

// ---------------------------------------------------------------------------
// K2: per (p,b): raw = x1^T @ x2 (K=196 padded to 224), centering correction,
//     column L2 normalize over d, write cov[b][p][d][e] fp32
// ---------------------------------------------------------------------------
__global__ __launch_bounds__(256, 2)
void k_cov(const bf16_t* __restrict__ hn, float* __restrict__ cov)
{
    __shared__ bf16_t x1s[128*40];
    __shared__ bf16_t x2s[128*40];
    __shared__ float rs1[128], rs2[128];
    __shared__ float colsq[2][128];
    __shared__ float nrm_inv[128];
    __shared__ float mu_s[2];

    const int t = threadIdx.x;
    const int lane = t & 63;
    const int wv = t >> 6;
    const int wr = wv >> 1, wc = wv & 1;
    const int q = lane >> 4;
    const int c = lane & 15;
    const int b = blockIdx.x;
    const int p = blockIdx.y;

    const bf16_t* X1 = hn + (((p*256 + b)*196) << 7);
    const bf16_t* X2 = hn + ((((p+1)*256 + b)*196) << 7);

    {
        const bf16_t* S = (t < 128) ? X1 : X2;
        const int d = t & 127;
        float s = 0.f;
        for (int n = 0; n < 196; n++) s += (float)S[(n << 7) + d];
        if (t < 128) rs1[d] = s; else rs2[d] = s;
    }
    __syncthreads();
    if (wv == 0) {
        float s = rs1[lane] + rs1[lane + 64];
#pragma unroll
        for (int o = 1; o < 64; o <<= 1) s += __shfl_xor(s, o);
        if (lane == 0) mu_s[0] = s * (1.f/(196.f*128.f));
    } else if (wv == 1) {
        float s = rs2[lane] + rs2[lane + 64];
#pragma unroll
        for (int o = 1; o < 64; o <<= 1) s += __shfl_xor(s, o);
        if (lane == 0) mu_s[1] = s * (1.f/(196.f*128.f));
    }

    floatx4 acc[4][4];
#pragma unroll
    for (int i = 0; i < 4; i++)
#pragma unroll
        for (int j = 0; j < 4; j++)
#pragma unroll
            for (int r = 0; r < 4; r++) acc[i][j][r] = 0.f;

    const int nl = t >> 3;
    const int d0 = (t & 7) * 16;

    for (int n0 = 0; n0 < 224; n0 += 32) {
        __syncthreads();
        const int n = n0 + nl;
        bf16x8 va, vb, wa, wb;
        if (n < 196) {
            const bf16_t* s1 = X1 + (n << 7) + d0;
            const bf16_t* s2 = X2 + (n << 7) + d0;
            va = *(const bf16x8*)s1;
            vb = *(const bf16x8*)(s1 + 8);
            wa = *(const bf16x8*)s2;
            wb = *(const bf16x8*)(s2 + 8);
        } else {
#pragma unroll
            for (int e = 0; e < 8; e++) {
                va[e] = (bf16_t)0.f; vb[e] = (bf16_t)0.f;
                wa[e] = (bf16_t)0.f; wb[e] = (bf16_t)0.f;
            }
        }
#pragma unroll
        for (int e = 0; e < 8; e++) {
            x1s[(d0 + e)*40 + nl]     = va[e];
            x1s[(d0 + 8 + e)*40 + nl] = vb[e];
            x2s[(d0 + e)*40 + nl]     = wa[e];
            x2s[(d0 + 8 + e)*40 + nl] = wb[e];
        }
        __syncthreads();
        bf16x8 af[4], bfr[4];
#pragma unroll
        for (int i = 0; i < 4; i++)
            af[i] = *(const bf16x8*)&x1s[(wr*64 + i*16 + c)*40 + q*8];
#pragma unroll
        for (int j = 0; j < 4; j++)
            bfr[j] = *(const bf16x8*)&x2s[(wc*64 + j*16 + c)*40 + q*8];
#pragma unroll
        for (int i = 0; i < 4; i++)
#pragma unroll
            for (int j = 0; j < 4; j++)
                acc[i][j] = __builtin_amdgcn_mfma_f32_16x16x32_bf16(af[i], bfr[j], acc[i][j], 0, 0, 0);
    }

    const float mu1 = mu_s[0], mu2 = mu_s[1];
    const float invL = 1.f/196.f;
    float csq[4] = {0.f, 0.f, 0.f, 0.f};
#pragma unroll
    for (int i = 0; i < 4; i++)
#pragma unroll
        for (int j = 0; j < 4; j++)
#pragma unroll
            for (int r = 0; r < 4; r++) {
                const int d = wr*64 + i*16 + q*4 + r;
                const int e = wc*64 + j*16 + c;
                const float v = acc[i][j][r]*invL - mu2*rs1[d]*invL - mu1*rs2[e]*invL + mu1*mu2;
                acc[i][j][r] = v;
                csq[j] += v*v;
            }
#pragma unroll
    for (int j = 0; j < 4; j++) {
        float s = csq[j];
        s += __shfl_xor(s, 16);
        s += __shfl_xor(s, 32);
        csq[j] = s;
    }
    if (q == 0) {
#pragma unroll
        for (int j = 0; j < 4; j++) colsq[wr][wc*64 + j*16 + c] = csq[j];
    }
    __syncthreads();
    if (t < 128) {
        const float nr = sqrtf(colsq[0][t] + colsq[1][t]);
        nrm_inv[t] = 1.f / fmaxf(nr, 1e-12f);
    }
    __syncthreads();
    float* dst = cov + ((long)b*3 + p)*16384;
#pragma unroll
    for (int i = 0; i < 4; i++)
#pragma unroll
        for (int j = 0; j < 4; j++) {
            const int e = wc*64 + j*16 + c;
            const float ni = nrm_inv[e];
#pragma unroll
            for (int r = 0; r < 4; r++) {
                const int d = wr*64 + i*16 + q*4 + r;
                dst[(d << 7) + e] = acc[i][j][r] * ni;
            }
        }
}

// ---------------------------------------------------------------------------
// K3a: conv1 (stride2 VALID) + exact GELU -> z1[b][o][63][63] fp32
// ---------------------------------------------------------------------------
__global__ __launch_bounds__(256)
void k_conv1(const float* __restrict__ cov, const float* __restrict__ w1,
             float* __restrict__ z1)
{
    __shared__ float W[27];
    const int t = threadIdx.x;
    const int b = blockIdx.x, o = blockIdx.y;
    if (t < 27) W[t] = w1[o*27 + t];
    __syncthreads();
    const float* C = cov + (long)b*3*16384;
    float* Z = z1 + ((long)b*3 + o)*3969;
    for (int idx = t; idx < 3969; idx += 256) {
        const int y = idx / 63, xx = idx - y*63;
        float a = 0.f;
#pragma unroll
        for (int i = 0; i < 3; i++) {
            const float* Ci = C + i*16384 + (2*y)*128 + 2*xx;
            const float* Wi = &W[i*9];
            a += Ci[0]*Wi[0]   + Ci[1]*Wi[1]   + Ci[2]*Wi[2]
               + Ci[128]*Wi[3] + Ci[129]*Wi[4] + Ci[130]*Wi[5]
               + Ci[256]*Wi[6] + Ci[257]*Wi[7] + Ci[258]*Wi[8];
        }
        Z[idx] = 0.5f*a*(1.0f + erff(a*0.70710678118654752f));
    }
}

// ---------------------------------------------------------------------------
// K3b: conv2 (stride2 VALID) -> bf16 into Xb[b][768 + idx] (classifier X)
// ---------------------------------------------------------------------------
__global__ __launch_bounds__(256)
void k_conv2(const float* __restrict__ z1, const float* __restrict__ w2,
             bf16_t* __restrict__ Xb)
{
    __shared__ float Z[3*3969];
    __shared__ float W[81];
    const int t = threadIdx.x, b = blockIdx.x;
    if (t < 81) W[t] = w2[t];
    const float* src = z1 + (long)b*3*3969;
    for (int idx = t; idx < 3*3969; idx += 256) Z[idx] = src[idx];
    __syncthreads();
    for (int idx = t; idx < 2883; idx += 256) {
        const int o = idx / 961, rem = idx - o*961;
        const int y = rem / 31, xx = rem - y*31;
        float a = 0.f;
#pragma unroll
        for (int i = 0; i < 3; i++) {
            const float* Zi = Z + i*3969 + (2*y)*63 + 2*xx;
            const float* Wi = &W[(o*3+i)*9];
            a += Zi[0]*Wi[0]   + Zi[1]*Wi[1]   + Zi[2]*Wi[2]
               + Zi[63]*Wi[3]  + Zi[64]*Wi[4]  + Zi[65]*Wi[5]
               + Zi[126]*Wi[6] + Zi[127]*Wi[7] + Zi[128]*Wi[8];
        }
        Xb[(long)b*3712 + 768 + idx] = (bf16_t)a;
    }
}

// ---------------------------------------------------------------------------
// K4a: cls fp32 -> bf16 into Xb[b][0..767]; zero K-pad [3651..3711]
// ---------------------------------------------------------------------------
__global__ __launch_bounds__(256)
void k_cvt_cls(const float* __restrict__ cls, bf16_t* __restrict__ Xb)
{
    const int t = threadIdx.x, b = blockIdx.x;
    for (int k = t; k < 768; k += 256)
        Xb[b*3712 + k] = (bf16_t)cls[b*768 + k];
    if (t < 61) Xb[b*3712 + 3651 + t] = (bf16_t)0.f;
}

// ---------------------------------------------------------------------------
// K4b: build Wb[n][k] bf16, n<1024 (1000 pad), k<3712 (3651 pad)
//      Wb[n][k] = k<768 ? W1[k][n] : W2[k-768][n]
// ---------------------------------------------------------------------------
__global__ __launch_bounds__(256)
void k_cvt_w(const float* __restrict__ W1, const float* __restrict__ W2,
             bf16_t* __restrict__ Wb)
{
    __shared__ bf16_t tile[32][33];
    const int k0 = blockIdx.x * 32;       // 116 tiles
    const int n0 = blockIdx.y * 32;       // 32 tiles
    const int tx = threadIdx.x & 31, ty = threadIdx.x >> 5;
    for (int i = ty; i < 32; i += 8) {
        const int k = k0 + i, n = n0 + tx;
        float v = 0.f;
        if (n < 1000 && k < 3651)
            v = (k < 768) ? W1[k*1000 + n] : W2[(k-768)*1000 + n];
        tile[i][tx] = (bf16_t)v;
    }
    __syncthreads();
    for (int i = ty; i < 32; i += 8)
        Wb[(n0 + i)*3712 + k0 + tx] = tile[tx][i];
}

// ---------------------------------------------------------------------------
// K4c: MFMA GEMM partial[s][m][n] = Xb[m][ks..] @ Wb[n][ks..]^T
// grid (nt=8, mt=2, split=4); 128x128 tile, K-split 928 each
// ---------------------------------------------------------------------------
__global__ __launch_bounds__(256, 2)
void k_gemm_cls(const bf16_t* __restrict__ Xb, const bf16_t* __restrict__ Wb,
                float* __restrict__ partial)
{
    __shared__ bf16_t As[128*32];
    __shared__ bf16_t Bs[128*32];

    const int t = threadIdx.x;
    const int lane = t & 63;
    const int wv = t >> 6;
    const int wr = wv >> 1, wc = wv & 1;
    const int q = lane >> 4;
    const int c = lane & 15;
    const int nt = blockIdx.x;
    const int mt = blockIdx.y;
    const int sp = blockIdx.z;

    const int srow  = t >> 2;
    const int skoff = (t & 3) * 8;
    const int m0 = mt * 128, n0 = nt * 128;
    const int kbase = sp * 928;
    const bf16_t* ag0 = Xb + (m0 + srow) * 3712 + kbase + skoff;
    const bf16_t* ag1 = Xb + (m0 + srow + 64) * 3712 + kbase + skoff;
    const bf16_t* bg0 = Wb + (n0 + srow) * 3712 + kbase + skoff;
    const bf16_t* bg1 = Wb + (n0 + srow + 64) * 3712 + kbase + skoff;

    floatx4 acc[4][4];
#pragma unroll
    for (int i = 0; i < 4; i++)
#pragma unroll
        for (int j = 0; j < 4; j++)
#pragma unroll
            for (int r = 0; r < 4; r++) acc[i][j][r] = 0.f;

    for (int k0 = 0; k0 < 928; k0 += 32) {
        __syncthreads();
        async_copy16(ag0 + k0, &As[t*8]);
        async_copy16(ag1 + k0, &As[2048 + t*8]);
        async_copy16(bg0 + k0, &Bs[t*8]);
        async_copy16(bg1 + k0, &Bs[2048 + t*8]);
        __syncthreads();
        bf16x8 af[4], bfr[4];
#pragma unroll
        for (int i = 0; i < 4; i++)
            af[i] = *(const bf16x8*)&As[(wr*64 + i*16 + c)*32 + q*8];
#pragma unroll
        for (int j = 0; j < 4; j++)
            bfr[j] = *(const bf16x8*)&Bs[(wc*64 + j*16 + c)*32 + q*8];
#pragma unroll
        for (int i = 0; i < 4; i++)
#pragma unroll
            for (int j = 0; j < 4; j++)
                acc[i][j] = __builtin_amdgcn_mfma_f32_16x16x32_bf16(af[i], bfr[j], acc[i][j], 0, 0, 0);
    }

    float* base = partial + ((long)sp*256 + m0)*1024 + n0;
#pragma unroll
    for (int i = 0; i < 4; i++)
#pragma unroll
        for (int r = 0; r < 4; r++) {
            const int row = wr*64 + i*16 + q*4 + r;
#pragma unroll
            for (int j = 0; j < 4; j++)
                base[row*1024 + wc*64 + j*16 + c] = acc[i][j][r];
        }
}

// ---------------------------------------------------------------------------
// K4d: out[m][n] = 0.5*(sum_s partial[s][m][n] + b1[n] + b2[n]), n<1000
// ---------------------------------------------------------------------------
__global__ __launch_bounds__(256)
void k_cls_fin(const float* __restrict__ partial, const float* __restrict__ b1,
               const float* __restrict__ b2, float* __restrict__ out)
{
    const int idx = blockIdx.x * 256 + threadIdx.x;   // 256,000
    const int m = idx / 1000, n = idx - m*1000;
    float s = partial[(m)*1024 + n] + partial[(256 + m)*1024 + n]
            + partial[(512 + m)*1024 + n] + partial[(768 + m)*1024 + n];
    out[idx] = 0.5f*(s + b1[n] + b2[n]);
}

// ---------------------------------------------------------------------------
extern "C" void kernel_launch(void* const* d_in, const int* in_sizes, int n_in,
                              void* d_out, int out_size, void* d_ws, size_t ws_size,
                              hipStream_t stream) {
    const float* cls = (const float*)d_in[0];
    const float* x   = (const float*)d_in[1];
    const float* pw  = (const float*)d_in[2];
    const float* pb  = (const float*)d_in[3];
    const float* lng = (const float*)d_in[4];
    const float* lnb = (const float*)d_in[5];
    const float* c1w = (const float*)d_in[6];
    const float* c2w = (const float*)d_in[7];
    const float* w1  = (const float*)d_in[8];
    const float* b1  = (const float*)d_in[9];
    const float* w2  = (const float*)d_in[10];
    const float* b2  = (const float*)d_in[11];

    char* ws = (char*)d_ws;
    // lifetimes (peak 115.4 MB):
    //   hn    [0, 51,380,224)                    proj_ln out -> cov in
    //   xbfh  [51,380,224, +38,535,168)          half-batch A, dead after proj_ln
    //   wt    [89,915,392, +786,432)             dead after proj_ln
    //   covb  [51,380,224, +50,331,648)          cov out -> conv1 in (reuses xbfh)
    //   z1    [0, +12,192,768)                   conv1 out -> conv2 in (reuses hn)
    //   Xb    [101,711,872, +1,900,544)          cls X (bf16, K=3712)
    //   Wb    [103,612,416, +7,602,176)          cls W^T (bf16)
    //   partial [111,214,592, +4,194,304)        K-split partials
    bf16_t* hn    = (bf16_t*)(ws);
    bf16_t* xbfh  = (bf16_t*)(ws + 51380224ull);
    bf16_t* wt    = (bf16_t*)(ws + 89915392ull);
    float*  covb  = (float*) (ws + 51380224ull);
    float*  z1    = (float*) (ws);
    bf16_t* Xb    = (bf16_t*)(ws + 101711872ull);
    bf16_t* Wb    = (bf16_t*)(ws + 103612416ull);
    float*  part  = (float*) (ws + 111214592ull);
    float*  out   = (float*)d_out;

    k_transpose_w<<<dim3(16, 24), 256, 0, stream>>>(pw, wt);
    // projection in two half-batches to cap workspace
    k_cvt_x<<<18816, 256, 0, stream>>>(x, xbfh, 0);
    k_proj_ln<<<dim3(196, 4), 256, 0, stream>>>(xbfh, wt, pb, lng, lnb, hn, 0);
    k_cvt_x<<<18816, 256, 0, stream>>>(x, xbfh, 128);
    k_proj_ln<<<dim3(196, 4), 256, 0, stream>>>(xbfh, wt, pb, lng, lnb, hn, 25088);
    // classifier transforms (regions disjoint from everything live)
    k_cvt_cls<<<256, 256, 0, stream>>>(cls, Xb);
    k_cvt_w<<<dim3(116, 32), 256, 0, stream>>>(w1, w2, Wb);
    // covariance + convs
    k_cov<<<dim3(256, 3), 256, 0, stream>>>(hn, covb);
    k_conv1<<<dim3(256, 3), 256, 0, stream>>>(covb, c1w, z1);
    k_conv2<<<256, 256, 0, stream>>>(z1, c2w, Xb);
    // classifier GEMM
    k_gemm_cls<<<dim3(8, 2, 4), 256, 0, stream>>>(Xb, Wb, part);
    k_cls_fin<<<1000, 256, 0, stream>>>(part, b1, b2, out);
}

// Round 4
// 433.229 us; speedup vs baseline: 1.9392x; 1.0181x over previous
//
#include <hip/hip_runtime.h>
#include <hip/hip_bf16.h>
#include <cstdint>

typedef __bf16 bf16_t;
typedef __bf16 bf16x4 __attribute__((ext_vector_type(4)));
typedef __bf16 bf16x8 __attribute__((ext_vector_type(8)));
typedef float floatx4 __attribute__((ext_vector_type(4)));

#define LNEPS 1e-5f

__device__ inline void async_copy16(const bf16_t* g, bf16_t* l) {
    __builtin_amdgcn_global_load_lds((const __attribute__((address_space(1))) void*)g,
                                     (__attribute__((address_space(3))) void*)l,
                                     16, 0, 0);
}

// ---------------------------------------------------------------------------
// K-1: convert x[:,1:,:] fp32 -> bf16 [50176][768] (16B stores)
// ---------------------------------------------------------------------------
__global__ __launch_bounds__(256)
void k_cvt_x(const float* __restrict__ x, bf16_t* __restrict__ xbf) {
    const int vid = blockIdx.x * 256 + threadIdx.x;   // 8-float chunk, 4,816,896 total
    const int row = vid / 96;                         // 0..50175
    const int kv  = vid - row * 96;
    const int b = row / 196, l = row - (row / 196) * 196;
    const float* src = x + ((b * 197 + l + 1) * 96 + kv) * 8;
    const floatx4 f0 = *(const floatx4*)src;
    const floatx4 f1 = *(const floatx4*)(src + 4);
    bf16x8 o;
#pragma unroll
    for (int e = 0; e < 4; e++) { o[e] = (bf16_t)f0[e]; o[e+4] = (bf16_t)f1[e]; }
    *(bf16x8*)(xbf + vid * 8) = o;
}

// ---------------------------------------------------------------------------
// K0: transpose proj_w (768x512 fp32) -> Wt (512x768 bf16), K-contig B operand
// ---------------------------------------------------------------------------
__global__ __launch_bounds__(256)
void k_transpose_w(const float* __restrict__ w, bf16_t* __restrict__ wt) {
    __shared__ bf16_t tile[32][33];
    const int bx = blockIdx.x;            // n-tile (16)
    const int by = blockIdx.y;            // k-tile (24)
    const int tx = threadIdx.x & 31, ty = threadIdx.x >> 5;  // 32x8
    for (int i = ty; i < 32; i += 8)
        tile[i][tx] = (bf16_t)w[(by*32 + i)*512 + bx*32 + tx];
    __syncthreads();
    for (int i = ty; i < 32; i += 8)
        wt[(bx*32 + i)*768 + by*32 + tx] = tile[tx][i];
}

// ---------------------------------------------------------------------------
// K1: xp = xbf @ Wt^T + b, fused per-head LayerNorm; write hn[h][b][n][d] bf16
// 128x256 tile (2 heads per block); head cols live in one wave -> shuffle-only LN
// ---------------------------------------------------------------------------
__global__ __launch_bounds__(256, 2)
void k_proj_ln(const bf16_t* __restrict__ xbf, const bf16_t* __restrict__ wt,
               const float* __restrict__ pb, const float* __restrict__ lng,
               const float* __restrict__ lnb, bf16_t* __restrict__ hn)
{
    __shared__ bf16_t As[128*32];
    __shared__ bf16_t Bs[256*32];

    const int t = threadIdx.x;
    const int lane = t & 63;
    const int wv = t >> 6;
    const int wr = wv >> 1, wc = wv & 1;
    const int q = lane >> 4;
    const int c = lane & 15;
    const int hp = blockIdx.y;            // head pair 0..1
    const int m0 = blockIdx.x * 128;

    const int srow  = t >> 2;
    const int skoff = (t & 3) * 8;
    const bf16_t* ag0 = xbf + (m0 + srow) * 768 + skoff;
    const bf16_t* ag1 = ag0 + 64*768;
    const bf16_t* bg0 = wt + (hp*256 + srow)*768 + skoff;

    floatx4 acc[4][8];
#pragma unroll
    for (int i = 0; i < 4; i++)
#pragma unroll
        for (int j = 0; j < 8; j++)
#pragma unroll
            for (int r = 0; r < 4; r++) acc[i][j][r] = 0.f;

    for (int k0 = 0; k0 < 768; k0 += 32) {
        __syncthreads();
        async_copy16(ag0 + k0, &As[t*8]);
        async_copy16(ag1 + k0, &As[2048 + t*8]);
        async_copy16(bg0 + k0,            &Bs[t*8]);
        async_copy16(bg0 + 64*768 + k0,   &Bs[2048 + t*8]);
        async_copy16(bg0 + 128*768 + k0,  &Bs[4096 + t*8]);
        async_copy16(bg0 + 192*768 + k0,  &Bs[6144 + t*8]);
        __syncthreads();
        bf16x8 af[4], bfr[8];
#pragma unroll
        for (int i = 0; i < 4; i++)
            af[i] = *(const bf16x8*)&As[(wr*64 + i*16 + c)*32 + q*8];
#pragma unroll
        for (int j = 0; j < 8; j++)
            bfr[j] = *(const bf16x8*)&Bs[(wc*128 + j*16 + c)*32 + q*8];
#pragma unroll
        for (int i = 0; i < 4; i++)
#pragma unroll
            for (int j = 0; j < 8; j++)
                acc[i][j] = __builtin_amdgcn_mfma_f32_16x16x32_bf16(af[i], bfr[j], acc[i][j], 0, 0, 0);
    }

    // epilogue: +bias, LayerNorm over this wave's head (128 cols = 8j x 16c)
    const int h = hp*2 + wc;
    float bias[8], gg[8], bb[8];
#pragma unroll
    for (int j = 0; j < 8; j++) {
        const int d = j*16 + c;
        bias[j] = pb[h*128 + d];
        gg[j]   = lng[d];
        bb[j]   = lnb[d];
    }
#pragma unroll
    for (int i = 0; i < 4; i++) {
#pragma unroll
        for (int r = 0; r < 4; r++) {
            float s = 0.f, s2 = 0.f;
#pragma unroll
            for (int j = 0; j < 8; j++) {
                const float v = acc[i][j][r] + bias[j];
                acc[i][j][r] = v;
                s += v; s2 += v*v;
            }
#pragma unroll
            for (int o = 1; o < 16; o <<= 1) { s += __shfl_xor(s, o); s2 += __shfl_xor(s2, o); }
            const float mu = s * (1.f/128.f);
            const float ms = s2 * (1.f/128.f);
            const float rstd = rsqrtf(ms - mu*mu + LNEPS);
            const int gm = m0 + wr*64 + i*16 + q*4 + r;
            const int bI = gm / 196, l = gm - bI*196;
            bf16_t* dst = hn + (((h*256 + bI)*196 + l) << 7);
#pragma unroll
            for (int j = 0; j < 8; j++) {
                const float v = (acc[i][j][r] - mu)*rstd*gg[j] + bb[j];
                dst[j*16 + c] = (bf16_t)v;
            }
        }
    }
}

// ---------------------------------------------------------------------------
// K1b: column sums over tokens: colsum[h][b][d] = sum_n hn[h][b][n][d]
// ---------------------------------------------------------------------------
__global__ __launch_bounds__(256)
void k_colsum(const bf16_t* __restrict__ hn, float* __restrict__ colsum)
{
    __shared__ float tmp[2][128];
    const int t = threadIdx.x;
    const int d = t & 127, half = t >> 7;
    const bf16_t* S = hn + ((long)blockIdx.x * 196 << 7);
    float s = 0.f;
    const int n0 = half * 98;
    for (int n = 0; n < 98; n++) s += (float)S[((n0 + n) << 7) + d];
    tmp[half][d] = s;
    __syncthreads();
    if (t < 128) colsum[(blockIdx.x << 7) + t] = tmp[0][t] + tmp[1][t];
}

// ---------------------------------------------------------------------------
// K2: per (p,b): raw = x1^T @ x2 (K=196 padded to 224), centering correction,
//     column L2 normalize over d, write cov[b][p][d][e] fp32
// ---------------------------------------------------------------------------
__global__ __launch_bounds__(256, 2)
void k_cov(const bf16_t* __restrict__ hn, const float* __restrict__ colsum,
           float* __restrict__ cov)
{
    __shared__ bf16_t x1s[128*40];
    __shared__ bf16_t x2s[128*40];
    __shared__ float rs1[128], rs2[128];
    __shared__ float colsq[2][128];
    __shared__ float nrm_inv[128];
    __shared__ float mu_s[2];

    const int t = threadIdx.x;
    const int lane = t & 63;
    const int wv = t >> 6;
    const int wr = wv >> 1, wc = wv & 1;
    const int q = lane >> 4;
    const int c = lane & 15;
    const int b = blockIdx.x;
    const int p = blockIdx.y;

    const bf16_t* X1 = hn + (((p*256 + b)*196) << 7);
    const bf16_t* X2 = hn + ((((p+1)*256 + b)*196) << 7);

    if (t < 128) rs1[t] = colsum[((p*256 + b) << 7) + t];
    else         rs2[t & 127] = colsum[(((p+1)*256 + b) << 7) + (t & 127)];
    __syncthreads();
    if (wv == 0) {
        float s = rs1[lane] + rs1[lane + 64];
#pragma unroll
        for (int o = 1; o < 64; o <<= 1) s += __shfl_xor(s, o);
        if (lane == 0) mu_s[0] = s * (1.f/(196.f*128.f));
    } else if (wv == 1) {
        float s = rs2[lane] + rs2[lane + 64];
#pragma unroll
        for (int o = 1; o < 64; o <<= 1) s += __shfl_xor(s, o);
        if (lane == 0) mu_s[1] = s * (1.f/(196.f*128.f));
    }

    floatx4 acc[4][4];
#pragma unroll
    for (int i = 0; i < 4; i++)
#pragma unroll
        for (int j = 0; j < 4; j++)
#pragma unroll
            for (int r = 0; r < 4; r++) acc[i][j][r] = 0.f;

    const int nl = t >> 3;
    const int d0 = (t & 7) * 16;

    for (int n0 = 0; n0 < 224; n0 += 32) {
        __syncthreads();
        const int n = n0 + nl;
        bf16x8 va, vb, wa, wb;
        if (n < 196) {
            const bf16_t* s1 = X1 + (n << 7) + d0;
            const bf16_t* s2 = X2 + (n << 7) + d0;
            va = *(const bf16x8*)s1;
            vb = *(const bf16x8*)(s1 + 8);
            wa = *(const bf16x8*)s2;
            wb = *(const bf16x8*)(s2 + 8);
        } else {
#pragma unroll
            for (int e = 0; e < 8; e++) {
                va[e] = (bf16_t)0.f; vb[e] = (bf16_t)0.f;
                wa[e] = (bf16_t)0.f; wb[e] = (bf16_t)0.f;
            }
        }
#pragma unroll
        for (int e = 0; e < 8; e++) {
            x1s[(d0 + e)*40 + nl]     = va[e];
            x1s[(d0 + 8 + e)*40 + nl] = vb[e];
            x2s[(d0 + e)*40 + nl]     = wa[e];
            x2s[(d0 + 8 + e)*40 + nl] = wb[e];
        }
        __syncthreads();
        bf16x8 af[4], bfr[4];
#pragma unroll
        for (int i = 0; i < 4; i++)
            af[i] = *(const bf16x8*)&x1s[(wr*64 + i*16 + c)*40 + q*8];
#pragma unroll
        for (int j = 0; j < 4; j++)
            bfr[j] = *(const bf16x8*)&x2s[(wc*64 + j*16 + c)*40 + q*8];
#pragma unroll
        for (int i = 0; i < 4; i++)
#pragma unroll
            for (int j = 0; j < 4; j++)
                acc[i][j] = __builtin_amdgcn_mfma_f32_16x16x32_bf16(af[i], bfr[j], acc[i][j], 0, 0, 0);
    }

    const float mu1 = mu_s[0], mu2 = mu_s[1];
    const float invL = 1.f/196.f;
    float csq[4] = {0.f, 0.f, 0.f, 0.f};
#pragma unroll
    for (int i = 0; i < 4; i++)
#pragma unroll
        for (int j = 0; j < 4; j++)
#pragma unroll
            for (int r = 0; r < 4; r++) {
                const int d = wr*64 + i*16 + q*4 + r;
                const int e = wc*64 + j*16 + c;
                const float v = acc[i][j][r]*invL - mu2*rs1[d]*invL - mu1*rs2[e]*invL + mu1*mu2;
                acc[i][j][r] = v;
                csq[j] += v*v;
            }
#pragma unroll
    for (int j = 0; j < 4; j++) {
        float s = csq[j];
        s += __shfl_xor(s, 16);
        s += __shfl_xor(s, 32);
        csq[j] = s;
    }
    if (q == 0) {
#pragma unroll
        for (int j = 0; j < 4; j++) colsq[wr][wc*64 + j*16 + c] = csq[j];
    }
    __syncthreads();
    if (t < 128) {
        const float nr = sqrtf(colsq[0][t] + colsq[1][t]);
        nrm_inv[t] = 1.f / fmaxf(nr, 1e-12f);
    }
    __syncthreads();
    float* dst = cov + ((long)b*3 + p)*16384;
#pragma unroll
    for (int i = 0; i < 4; i++)
#pragma unroll
        for (int j = 0; j < 4; j++) {
            const int e = wc*64 + j*16 + c;
            const float ni = nrm_inv[e];
#pragma unroll
            for (int r = 0; r < 4; r++) {
                const int d = wr*64 + i*16 + q*4 + r;
                dst[(d << 7) + e] = acc[i][j][r] * ni;
            }
        }
}

// ---------------------------------------------------------------------------
// K3: fused conv1+GELU+conv2 per batch; z1 kept in LDS; out -> Xb[b][768+...]
// ---------------------------------------------------------------------------
__global__ __launch_bounds__(256)
void k_convs(const float* __restrict__ cov, const float* __restrict__ w1,
             const float* __restrict__ w2, bf16_t* __restrict__ Xb)
{
    __shared__ float Z[3*3969];
    __shared__ float W1s[81];
    __shared__ float W2s[81];
    const int t = threadIdx.x, b = blockIdx.x;
    if (t < 81) { W1s[t] = w1[t]; W2s[t] = w2[t]; }
    __syncthreads();
    const float* C = cov + (long)b*3*16384;
    for (int idx = t; idx < 3*3969; idx += 256) {
        const int o = idx / 3969, rem = idx - o*3969;
        const int y = rem / 63, xx = rem - y*63;
        float a = 0.f;
#pragma unroll
        for (int i = 0; i < 3; i++) {
            const float* Ci = C + i*16384 + (2*y)*128 + 2*xx;
            const float* Wi = &W1s[o*27 + i*9];
            a += Ci[0]*Wi[0]   + Ci[1]*Wi[1]   + Ci[2]*Wi[2]
               + Ci[128]*Wi[3] + Ci[129]*Wi[4] + Ci[130]*Wi[5]
               + Ci[256]*Wi[6] + Ci[257]*Wi[7] + Ci[258]*Wi[8];
        }
        Z[idx] = 0.5f*a*(1.0f + erff(a*0.70710678118654752f));
    }
    __syncthreads();
    for (int idx = t; idx < 2883; idx += 256) {
        const int o = idx / 961, rem = idx - o*961;
        const int y = rem / 31, xx = rem - y*31;
        float a = 0.f;
#pragma unroll
        for (int i = 0; i < 3; i++) {
            const float* Zi = Z + i*3969 + (2*y)*63 + 2*xx;
            const float* Wi = &W2s[(o*3+i)*9];
            a += Zi[0]*Wi[0]   + Zi[1]*Wi[1]   + Zi[2]*Wi[2]
               + Zi[63]*Wi[3]  + Zi[64]*Wi[4]  + Zi[65]*Wi[5]
               + Zi[126]*Wi[6] + Zi[127]*Wi[7] + Zi[128]*Wi[8];
        }
        Xb[(long)b*3712 + 768 + idx] = (bf16_t)a;
    }
}

// ---------------------------------------------------------------------------
// K4a: cls fp32 -> bf16 into Xb[b][0..767]; zero K-pad [3651..3711]
// ---------------------------------------------------------------------------
__global__ __launch_bounds__(256)
void k_cvt_cls(const float* __restrict__ cls, bf16_t* __restrict__ Xb)
{
    const int t = threadIdx.x, b = blockIdx.x;
    for (int k = t; k < 768; k += 256)
        Xb[b*3712 + k] = (bf16_t)cls[b*768 + k];
    if (t < 61) Xb[b*3712 + 3651 + t] = (bf16_t)0.f;
}

// ---------------------------------------------------------------------------
// K4b: build Wb[n][k] bf16, n<1024 (1000 pad), k<3712 (3651 pad)
// ---------------------------------------------------------------------------
__global__ __launch_bounds__(256)
void k_cvt_w(const float* __restrict__ W1, const float* __restrict__ W2,
             bf16_t* __restrict__ Wb)
{
    __shared__ bf16_t tile[32][33];
    const int k0 = blockIdx.x * 32;       // 116 tiles
    const int n0 = blockIdx.y * 32;       // 32 tiles
    const int tx = threadIdx.x & 31, ty = threadIdx.x >> 5;
    for (int i = ty; i < 32; i += 8) {
        const int k = k0 + i, n = n0 + tx;
        float v = 0.f;
        if (n < 1000 && k < 3651)
            v = (k < 768) ? W1[k*1000 + n] : W2[(k-768)*1000 + n];
        tile[i][tx] = (bf16_t)v;
    }
    __syncthreads();
    for (int i = ty; i < 32; i += 8)
        Wb[(n0 + i)*3712 + k0 + tx] = tile[tx][i];
}

// ---------------------------------------------------------------------------
// K4c: MFMA GEMM partial[s][m][n] = Xb[m][ks..] @ Wb[n][ks..]^T
// grid (nt=8, mt=2, split=4); 128x128 tile, K-split 928 each
// ---------------------------------------------------------------------------
__global__ __launch_bounds__(256, 2)
void k_gemm_cls(const bf16_t* __restrict__ Xb, const bf16_t* __restrict__ Wb,
                float* __restrict__ partial)
{
    __shared__ bf16_t As[128*32];
    __shared__ bf16_t Bs[128*32];

    const int t = threadIdx.x;
    const int lane = t & 63;
    const int wv = t >> 6;
    const int wr = wv >> 1, wc = wv & 1;
    const int q = lane >> 4;
    const int c = lane & 15;
    const int nt = blockIdx.x;
    const int mt = blockIdx.y;
    const int sp = blockIdx.z;

    const int srow  = t >> 2;
    const int skoff = (t & 3) * 8;
    const int m0 = mt * 128, n0 = nt * 128;
    const int kbase = sp * 928;
    const bf16_t* ag0 = Xb + (m0 + srow) * 3712 + kbase + skoff;
    const bf16_t* ag1 = Xb + (m0 + srow + 64) * 3712 + kbase + skoff;
    const bf16_t* bg0 = Wb + (n0 + srow) * 3712 + kbase + skoff;
    const bf16_t* bg1 = Wb + (n0 + srow + 64) * 3712 + kbase + skoff;

    floatx4 acc[4][4];
#pragma unroll
    for (int i = 0; i < 4; i++)
#pragma unroll
        for (int j = 0; j < 4; j++)
#pragma unroll
            for (int r = 0; r < 4; r++) acc[i][j][r] = 0.f;

    for (int k0 = 0; k0 < 928; k0 += 32) {
        __syncthreads();
        async_copy16(ag0 + k0, &As[t*8]);
        async_copy16(ag1 + k0, &As[2048 + t*8]);
        async_copy16(bg0 + k0, &Bs[t*8]);
        async_copy16(bg1 + k0, &Bs[2048 + t*8]);
        __syncthreads();
        bf16x8 af[4], bfr[4];
#pragma unroll
        for (int i = 0; i < 4; i++)
            af[i] = *(const bf16x8*)&As[(wr*64 + i*16 + c)*32 + q*8];
#pragma unroll
        for (int j = 0; j < 4; j++)
            bfr[j] = *(const bf16x8*)&Bs[(wc*64 + j*16 + c)*32 + q*8];
#pragma unroll
        for (int i = 0; i < 4; i++)
#pragma unroll
            for (int j = 0; j < 4; j++)
                acc[i][j] = __builtin_amdgcn_mfma_f32_16x16x32_bf16(af[i], bfr[j], acc[i][j], 0, 0, 0);
    }

    float* base = partial + ((long)sp*256 + m0)*1024 + n0;
#pragma unroll
    for (int i = 0; i < 4; i++)
#pragma unroll
        for (int r = 0; r < 4; r++) {
            const int row = wr*64 + i*16 + q*4 + r;
#pragma unroll
            for (int j = 0; j < 4; j++)
                base[row*1024 + wc*64 + j*16 + c] = acc[i][j][r];
        }
}

// ---------------------------------------------------------------------------
// K4d: out[m][n] = 0.5*(sum_s partial[s][m][n] + b1[n] + b2[n]), n<1000
// ---------------------------------------------------------------------------
__global__ __launch_bounds__(256)
void k_cls_fin(const float* __restrict__ partial, const float* __restrict__ b1,
               const float* __restrict__ b2, float* __restrict__ out)
{
    const int idx = blockIdx.x * 256 + threadIdx.x;   // 256,000
    const int m = idx / 1000, n = idx - m*1000;
    float s = partial[(m)*1024 + n] + partial[(256 + m)*1024 + n]
            + partial[(512 + m)*1024 + n] + partial[(768 + m)*1024 + n];
    out[idx] = 0.5f*(s + b1[n] + b2[n]);
}

// ---------------------------------------------------------------------------
extern "C" void kernel_launch(void* const* d_in, const int* in_sizes, int n_in,
                              void* d_out, int out_size, void* d_ws, size_t ws_size,
                              hipStream_t stream) {
    const float* cls = (const float*)d_in[0];
    const float* x   = (const float*)d_in[1];
    const float* pw  = (const float*)d_in[2];
    const float* pb  = (const float*)d_in[3];
    const float* lng = (const float*)d_in[4];
    const float* lnb = (const float*)d_in[5];
    const float* c1w = (const float*)d_in[6];
    const float* c2w = (const float*)d_in[7];
    const float* w1  = (const float*)d_in[8];
    const float* b1  = (const float*)d_in[9];
    const float* w2  = (const float*)d_in[10];
    const float* b2  = (const float*)d_in[11];

    char* ws = (char*)d_ws;
    // lifetimes (peak ~143.5 MB; ws ~600 MB per round-3 fill WRITE_SIZE):
    //   hn      [0, 51,380,224)                 proj_ln out -> colsum/cov in
    //   xbf     [51,380,224, +77,070,336)       dead after proj_ln
    //   wt      [128,450,560, +786,432)         dead after proj_ln
    //   covb    [51,380,224, +50,331,648)       reuses xbf; cov out -> convs in
    //   colsum  [129,236,992, +524,288)
    //   Xb      [129,761,280, +1,900,544)
    //   Wb      [131,661,824, +7,602,176)
    //   part    [139,264,000, +4,194,304)
    bf16_t* hn    = (bf16_t*)(ws);
    bf16_t* xbf   = (bf16_t*)(ws + 51380224ull);
    bf16_t* wt    = (bf16_t*)(ws + 128450560ull);
    float*  covb  = (float*) (ws + 51380224ull);
    float*  csum  = (float*) (ws + 129236992ull);
    bf16_t* Xb    = (bf16_t*)(ws + 129761280ull);
    bf16_t* Wb    = (bf16_t*)(ws + 131661824ull);
    float*  part  = (float*) (ws + 139264000ull);
    float*  out   = (float*)d_out;

    k_transpose_w<<<dim3(16, 24), 256, 0, stream>>>(pw, wt);
    k_cvt_x<<<18816, 256, 0, stream>>>(x, xbf);
    k_cvt_cls<<<256, 256, 0, stream>>>(cls, Xb);
    k_cvt_w<<<dim3(116, 32), 256, 0, stream>>>(w1, w2, Wb);
    k_proj_ln<<<dim3(392, 2), 256, 0, stream>>>(xbf, wt, pb, lng, lnb, hn);
    k_colsum<<<1024, 256, 0, stream>>>(hn, csum);
    k_cov<<<dim3(256, 3), 256, 0, stream>>>(hn, csum, covb);
    k_convs<<<256, 256, 0, stream>>>(covb, c1w, c2w, Xb);
    k_gemm_cls<<<dim3(8, 2, 4), 256, 0, stream>>>(Xb, Wb, part);
    k_cls_fin<<<1000, 256, 0, stream>>>(part, b1, b2, out);
}